// Round 8
// baseline (148.435 us; speedup 1.0000x reference)
//
#include <hip/hip_runtime.h>
#include <hip/hip_bf16.h>

#define LATN 512
#define FINN 256
#define FOUTN 256
#define NB 16
#define HH 64
#define WW 64

typedef __attribute__((ext_vector_type(8))) short bf16x8;
typedef __attribute__((ext_vector_type(4))) float f32x4;
typedef __attribute__((ext_vector_type(4))) int i32x4;

// ------- workspace byte offsets -------
#define WS_ZERO   0           // 256 B
#define WS_MW2    4096        // 256*256*4 = 262144
#define WS_DCO    266240      // 16*256*4  = 16384
#define WS_SNORM  282624      // 16*256*4  = 16384
#define WS_WFMT   299008      // 4*294912  = 1179648
#define WS_XM     1478656     // 16*2097152 = 33554432
// style ping-pong buffers ALIAS the xm region (dead until xcvt runs):
#define WS_HA     (WS_XM)            // 16*512*4
#define WS_HB     (WS_XM + 32768)    // 16*512*4
#define WS_STY    (WS_XM + 65536)    // 16*256*4
// xm layout  : [b][chunk(8)][pos(4096)][slot(4)] granules of 16B (8 bf16 ch), slot = iq ^ sigma(h,w)
// wfmt layout: [obi(4)][chunk(8)][tap(9)][ol(64)][slot(4)] granules, slot = iq ^ ((ol>>1)&3)

// ================= weight prep: swizzled wfmt + mw2 + zerobuf =================
__global__ void weight_prep_kernel(const float* __restrict__ weight,
                                   __hip_bfloat16* __restrict__ wfmt,
                                   float* __restrict__ mw2sum,
                                   float* __restrict__ zerobuf) {
    __shared__ float red[256];
    int o = blockIdx.x, t = threadIdx.x;
    if (o == 0 && t < 64) zerobuf[t] = 0.f;
    const float* wrow = weight + ((size_t)o * FINN + t) * 9;
    float wv[9];
    float mx = 0.f;
    #pragma unroll
    for (int k = 0; k < 9; ++k) { wv[k] = wrow[k]; mx = fmaxf(mx, fabsf(wv[k])); }
    red[t] = mx;
    __syncthreads();
    for (int k = 128; k > 0; k >>= 1) {
        if (t < k) red[t] = fmaxf(red[t], red[t + k]);
        __syncthreads();
    }
    float scale = (1.0f / 48.0f) / red[0];
    int obi = o >> 6, ol = o & 63, ch = t >> 5, il = t & 31;
    int slot = (il >> 3) ^ ((ol >> 1) & 3);
    char* basep = (char*)wfmt + (size_t)obi * 294912 + (size_t)ch * 36864
                + (size_t)ol * 64 + slot * 16 + (il & 7) * 2;
    float s2 = 0.f;
    #pragma unroll
    for (int tap = 0; tap < 9; ++tap) {
        float m = wv[tap] * scale;
        s2 += m * m;
        *(__hip_bfloat16*)(basep + tap * 4096) = __float2bfloat16(m);
    }
    mw2sum[(size_t)o * FINN + t] = s2;
}

// ================= style MLP layer (parallel over j across blocks) =================
__global__ __launch_bounds__(256) void style_layer_kernel(
    const float* __restrict__ in, const float* __restrict__ w,
    const float* __restrict__ bias, float* __restrict__ out,
    int in_dim_v4, int out_dim, float scale, int do_lrelu) {
    int t = threadIdx.x;
    int jl = t >> 4, kl = t & 15;
    int j = blockIdx.x * 16 + jl;
    int b = blockIdx.y;
    const float4* inr = (const float4*)(in + (size_t)b * (in_dim_v4 * 4));
    const float4* wr  = (const float4*)(w + (size_t)j * (in_dim_v4 * 4));
    float sum = 0.f;
    #pragma unroll 4
    for (int kb = kl; kb < in_dim_v4; kb += 16) {
        float4 wv = wr[kb], iv = inr[kb];
        sum += wv.x * iv.x + wv.y * iv.y + wv.z * iv.z + wv.w * iv.w;
    }
    #pragma unroll
    for (int off = 8; off >= 1; off >>= 1)
        sum += __shfl_xor(sum, off, 16);
    if (kl == 0) {
        float v = sum * scale + bias[j];
        if (do_lrelu && v < 0.f) v *= 0.2f;
        out[(size_t)b * out_dim + j] = v;
    }
}

// ================= fused inf-norm + dcoef =================
__global__ __launch_bounds__(256) void norm_dcoef_kernel(
    const float* __restrict__ sty, const float* __restrict__ mw2,
    float* __restrict__ snorm, float* __restrict__ dco) {
    __shared__ float red[256];
    __shared__ float s2[256];
    int b = blockIdx.x, t = threadIdx.x;
    float v = sty[(size_t)b * FINN + t];
    red[t] = fabsf(v);
    __syncthreads();
    for (int k = 128; k > 0; k >>= 1) {
        if (t < k) red[t] = fmaxf(red[t], red[t + k]);
        __syncthreads();
    }
    float sv = v / red[0];
    snorm[(size_t)b * FINN + t] = sv;
    s2[t] = sv * sv;
    __syncthreads();
    const float4* m2 = (const float4*)(mw2 + (size_t)t * FINN);
    const float4* sq = (const float4*)s2;
    float sum = 0.f;
    #pragma unroll 8
    for (int kb = 0; kb < 64; ++kb) {
        float4 a = m2[kb], xq = sq[kb];
        sum += a.x * xq.x + a.y * xq.y + a.z * xq.z + a.w * xq.w;
    }
    dco[(size_t)b * FOUTN + t] = rsqrtf(sum + 1e-8f);
}

// ================= x NCHW fp32 -> swizzled chunk-major bf16 xm =================
__global__ __launch_bounds__(256) void xcvt_kernel(const float* __restrict__ x,
                                                   const float* __restrict__ sn,
                                                   char* __restrict__ xm) {
    __shared__ float tile[64][65];
    int h = blockIdx.x, b = blockIdx.y;
    int t = threadIdx.x;
    int wl_ = t & 63, ig = t >> 6;
    char* xmb = xm + (size_t)b * 2097152;
    for (int icb = 0; icb < 4; ++icb) {
        if (icb) __syncthreads();
        #pragma unroll
        for (int p = 0; p < 16; ++p) {
            int i_l = p * 4 + ig;
            int i = icb * 64 + i_l;
            tile[i_l][wl_] = x[((size_t)(b * FINN + i)) * 4096 + h * 64 + wl_]
                             * sn[(size_t)b * FINN + i];
        }
        __syncthreads();
        #pragma unroll
        for (int rep = 0; rep < 2; ++rep) {
            int g = rep * 256 + t;     // 0..511
            int w = g >> 3, q8 = g & 7;
            int chunk = icb * 2 + (q8 >> 2), iq = q8 & 3;
            int slot = iq ^ (((h + 1) + ((w + 1) >> 1)) & 3);
            short tmp[8];
            #pragma unroll
            for (int j = 0; j < 8; ++j) {
                __hip_bfloat16 hb = __float2bfloat16(tile[q8 * 8 + j][w]);
                tmp[j] = *(short*)&hb;
            }
            char* dst = xmb + (size_t)chunk * 262144 + (size_t)(h * 64 + w) * 64 + slot * 16;
            *(bf16x8*)dst = *(bf16x8*)tmp;
        }
    }
}

// ================= global_load_lds helper =================
__device__ __forceinline__ void gl_lds16(const void* g, void* l) {
    __builtin_amdgcn_global_load_lds(
        (const __attribute__((address_space(1))) unsigned int*)g,
        (__attribute__((address_space(3))) unsigned int*)l, 16, 0, 0);
}

// ---- fragment helpers: 2-row (N=128) register tile ----
__device__ __forceinline__ void rd_tap2(bf16x8* xf, bf16x8* wf,
                                        const char* xsb, const char* wlb,
                                        int wid, int l15, int lg, int wfrag,
                                        int kh, int kw) {
    int tap = kh * 3 + kw;
    int pa = (wid * 2 + kh) * 66 + kw + l15;
    int pb = pa + 66;
    int xa = pa * 64 + ((lg ^ ((pa >> 1) & 3)) << 4);
    int xb = pb * 64 + ((lg ^ ((pb >> 1) & 3)) << 4);
    #pragma unroll
    for (int nt = 0; nt < 4; ++nt)
        xf[nt] = *(const bf16x8*)(xsb + xa + nt * 1024);
    #pragma unroll
    for (int nt = 0; nt < 4; ++nt)
        xf[4 + nt] = *(const bf16x8*)(xsb + xb + nt * 1024);
    #pragma unroll
    for (int mt = 0; mt < 4; ++mt)
        wf[mt] = *(const bf16x8*)(wlb + tap * 4096 + mt * 1024 + wfrag);
}

__device__ __forceinline__ void mm_tap2(f32x4 acc[4][8], const bf16x8* xf, const bf16x8* wf) {
    #pragma unroll
    for (int mt = 0; mt < 4; ++mt)
        #pragma unroll
        for (int nt = 0; nt < 8; ++nt)
            acc[mt][nt] = __builtin_amdgcn_mfma_f32_16x16x32_bf16(
                wf[mt], xf[nt], acc[mt][nt], 0, 0, 0);
}

// pipelined step: read next tap's 12 frags, wait for current tap's, MFMA current
#define STEP2(XFN, WFN, KH, KW, XFC, WFC)                               \
    rd_tap2(XFN, WFN, xs, wlb, wid, l15, lg, wfrag, KH, KW);            \
    __builtin_amdgcn_sched_barrier(0);                                  \
    asm volatile("s_waitcnt lgkmcnt(12)" ::: "memory");                 \
    __builtin_amdgcn_sched_barrier(0);                                  \
    __builtin_amdgcn_s_setprio(1);                                      \
    mm_tap2(acc, XFC, WFC);                                             \
    __builtin_amdgcn_s_setprio(0);

// ================= MFMA conv: 16-row block, 2 rows/wave, w-dbuf =================
// grid (4 htile, 4 obi, 16 b) = 256 blocks (1/CU), 512 threads (8 waves).
// Wave wid computes O=64 x rows {h0+2wid, h0+2wid+1} x 64 w (4x8 frags).
__global__ __launch_bounds__(512, 2) void mconv_kernel(
    const char* __restrict__ xm, const char* __restrict__ wfmt,
    const float* __restrict__ dco, float* __restrict__ y) {
    __shared__ char xs[76032];      // 18 rows x 66 cols x 64B, swizzled slots
    __shared__ char wl[2][36864];   // dbuf [tap 9][o 64][slot 4] granules

    int t = threadIdx.x;
    int lane = t & 63;
    int wid = t >> 6;
    int h0 = blockIdx.x * 16;
    int obi = blockIdx.y;
    int b = blockIdx.z;

    // zero halo columns (c=0,65) for all rows; never staged
    if (t < 144) {
        int r = t >> 3, sub = t & 7;
        int col = (sub >> 2) * 65, slot = sub & 3;
        *(i32x4*)(xs + ((r * 66 + col) * 4 + slot) * 16) = (i32x4){0, 0, 0, 0};
    }
    // zero out-of-range full rows (r=0 at htile 0; r=17 at htile 3); staging skips them
    if (h0 == 0) {
        for (int e = t; e < 256; e += 512)
            *(i32x4*)(xs + ((0 * 66 + 1 + (e >> 2)) * 4 + (e & 3)) * 16) = (i32x4){0, 0, 0, 0};
    }
    if (h0 == 48) {
        for (int e = t; e < 256; e += 512)
            *(i32x4*)(xs + ((17 * 66 + 1 + (e >> 2)) * 4 + (e & 3)) * 16) = (i32x4){0, 0, 0, 0};
    }

    // x staging: 72 issues/chunk (18 rows x 4 quarters), 9 per wave; 32-bit offsets
    const char* xmb = xm + (size_t)b * 2097152 + lane * 16;
    unsigned xoff[9], xdst[9];
    bool xval[9];
    #pragma unroll
    for (int q = 0; q < 9; ++q) {
        int idx = wid * 9 + q;
        int r = idx >> 2, quarter = idx & 3;
        int gh = h0 - 1 + r;
        xval[q] = (gh >= 0) && (gh < HH);
        xoff[q] = (unsigned)((gh * 64 + quarter * 16) * 64);
        xdst[q] = (unsigned)((r * 66 + 1) * 64 + quarter * 1024);
    }
    // w staging: 36 issues/chunk; waves 0..3 take 5, waves 4..7 take 4
    const char* wlane = wfmt + (size_t)obi * 294912 + lane * 16;

    f32x4 acc[4][8] = {};
    int l15 = lane & 15, lg = lane >> 4;
    int wfrag = l15 * 64 + ((lg ^ ((l15 >> 1) & 3)) << 4);

    // ---- prologue: stage w chunk 0 into wl[0] ----
    #pragma unroll
    for (int q = 0; q < 5; ++q) {
        int idx = wid + q * 8;
        if (idx < 36) gl_lds16(wlane + idx * 1024, wl[0] + idx * 1024);
    }
    wlane += 36864;

    for (int ch = 0; ch < 8; ++ch) {
        int cur = ch & 1;
        // x for this chunk (oldest in queue after prev-w)
        const char* xch = xmb + (size_t)ch * 262144;
        #pragma unroll
        for (int q = 0; q < 9; ++q)
            if (xval[q]) gl_lds16(xch + xoff[q], xs + xdst[q]);
        // w for next chunk (newest; stays in flight across barrier+compute)
        if (ch < 7) {
            #pragma unroll
            for (int q = 0; q < 5; ++q) {
                int idx = wid + q * 8;
                if (idx < 36) gl_lds16(wlane + idx * 1024, wl[cur ^ 1] + idx * 1024);
            }
            wlane += 36864;
            if (wid < 4) asm volatile("s_waitcnt vmcnt(5)" ::: "memory");
            else         asm volatile("s_waitcnt vmcnt(4)" ::: "memory");
        } else {
            asm volatile("s_waitcnt vmcnt(0)" ::: "memory");
        }
        asm volatile("s_waitcnt lgkmcnt(0)" ::: "memory");  // halo ds_writes (ch 0)
        __builtin_amdgcn_s_barrier();
        __builtin_amdgcn_sched_barrier(0);

        const char* wlb = wl[cur];
        // ---- tap pipeline: 2 frag banks, counted lgkm waits ----
        bf16x8 xf0[8], wf0[4], xf1[8], wf1[4];
        rd_tap2(xf0, wf0, xs, wlb, wid, l15, lg, wfrag, 0, 0);
        STEP2(xf1, wf1, 0, 1, xf0, wf0)
        STEP2(xf0, wf0, 0, 2, xf1, wf1)
        STEP2(xf1, wf1, 1, 0, xf0, wf0)
        STEP2(xf0, wf0, 1, 1, xf1, wf1)
        STEP2(xf1, wf1, 1, 2, xf0, wf0)
        STEP2(xf0, wf0, 2, 0, xf1, wf1)
        STEP2(xf1, wf1, 2, 1, xf0, wf0)
        STEP2(xf0, wf0, 2, 2, xf1, wf1)
        __builtin_amdgcn_sched_barrier(0);
        asm volatile("s_waitcnt lgkmcnt(0)" ::: "memory");
        __builtin_amdgcn_sched_barrier(0);
        __builtin_amdgcn_s_setprio(1);
        mm_tap2(acc, xf0, wf0);
        __builtin_amdgcn_s_setprio(0);

        __builtin_amdgcn_s_barrier();   // release xs and wl[cur] for overwrite
        __builtin_amdgcn_sched_barrier(0);
    }

    // epilogue: demod + store (2 rows per wave)
    const float* dcb = dco + (size_t)b * FOUTN + obi * 64;
    #pragma unroll
    for (int rr = 0; rr < 2; ++rr) {
        float* yb = y + (((size_t)b * FOUTN + obi * 64) * HH + (h0 + wid * 2 + rr)) * WW;
        #pragma unroll
        for (int mt = 0; mt < 4; ++mt) {
            #pragma unroll
            for (int j = 0; j < 4; ++j) {
                int o_l = mt * 16 + lg * 4 + j;
                float d = dcb[o_l];
                #pragma unroll
                for (int n4 = 0; n4 < 4; ++n4)
                    yb[(size_t)o_l * 4096 + n4 * 16 + l15] = acc[mt][rr * 4 + n4][j] * d;
            }
        }
    }
}

extern "C" void kernel_launch(void* const* d_in, const int* in_sizes, int n_in,
                              void* d_out, int out_size, void* d_ws, size_t ws_size,
                              hipStream_t stream) {
    const float* x      = (const float*)d_in[0];
    const float* lat    = (const float*)d_in[1];
    const float* weight = (const float*)d_in[2];
    const float* wsm    = (const float*)d_in[3];
    const float* bsm    = (const float*)d_in[4];
    const float* wff    = (const float*)d_in[5];
    const float* bff    = (const float*)d_in[6];
    float* y = (float*)d_out;

    char* base = (char*)d_ws;
    float* zerobuf = (float*)(base + WS_ZERO);
    float* mw2     = (float*)(base + WS_MW2);
    float* dco     = (float*)(base + WS_DCO);
    float* snorm   = (float*)(base + WS_SNORM);
    __hip_bfloat16* wfmt = (__hip_bfloat16*)(base + WS_WFMT);
    char* xm       = base + WS_XM;
    float* hA      = (float*)(base + WS_HA);
    float* hB      = (float*)(base + WS_HB);
    float* sty     = (float*)(base + WS_STY);

    const float eq = 0.044194173824159216f;  // 1/sqrt(512)

    weight_prep_kernel<<<FOUTN, 256, 0, stream>>>(weight, wfmt, mw2, zerobuf);
    style_layer_kernel<<<dim3(LATN / 16, NB), 256, 0, stream>>>(
        lat, wsm + 0 * (size_t)LATN * LATN, bsm + 0 * LATN, hA, LATN / 4, LATN, eq, 1);
    style_layer_kernel<<<dim3(LATN / 16, NB), 256, 0, stream>>>(
        hA, wsm + 1 * (size_t)LATN * LATN, bsm + 1 * LATN, hB, LATN / 4, LATN, eq, 1);
    style_layer_kernel<<<dim3(LATN / 16, NB), 256, 0, stream>>>(
        hB, wsm + 2 * (size_t)LATN * LATN, bsm + 2 * LATN, hA, LATN / 4, LATN, eq, 1);
    style_layer_kernel<<<dim3(LATN / 16, NB), 256, 0, stream>>>(
        hA, wsm + 3 * (size_t)LATN * LATN, bsm + 3 * LATN, hB, LATN / 4, LATN, eq, 1);
    style_layer_kernel<<<dim3(FINN / 16, NB), 256, 0, stream>>>(
        hB, wff, bff, sty, LATN / 4, FINN, 1.0f, 0);
    norm_dcoef_kernel<<<NB, 256, 0, stream>>>(sty, mw2, snorm, dco);
    xcvt_kernel<<<dim3(HH, NB), 256, 0, stream>>>(x, snorm, xm);
    mconv_kernel<<<dim3(4, 4, NB), 512, 0, stream>>>(xm, (const char*)wfmt, dco, y);
}

// Round 9
// 126.066 us; speedup vs baseline: 1.1774x; 1.1774x over previous
//
#include <hip/hip_runtime.h>
#include <hip/hip_bf16.h>

#define LATN 512
#define FINN 256
#define FOUTN 256
#define NB 16
#define HH 64
#define WW 64

typedef __attribute__((ext_vector_type(8))) short bf16x8;
typedef __attribute__((ext_vector_type(4))) float f32x4;
typedef __attribute__((ext_vector_type(4))) int i32x4;

// ------- workspace byte offsets -------
#define WS_ZERO   0           // 256 B
#define WS_MW2    4096        // 256*256*4 = 262144
#define WS_DCO    266240      // 16*256*4  = 16384
#define WS_SNORM  282624      // 16*256*4  = 16384
#define WS_WFMT   299008      // 4*294912  = 1179648
#define WS_XM     1478656     // 16*2097152 = 33554432
// style ping-pong buffers ALIAS the xm region (dead until xcvt runs):
#define WS_HA     (WS_XM)            // 16*512*4
#define WS_HB     (WS_XM + 32768)    // 16*512*4
#define WS_STY    (WS_XM + 65536)    // 16*256*4
// xm layout  : [b][chunk(8)][pos(4096)][slot(4)] granules of 16B (8 bf16 ch), slot = iq ^ sigma(h,w)
// wfmt layout: [obi(4)][chunk(8)][tap(9)][ol(64)][slot(4)] granules, slot = iq ^ ((ol>>1)&3)

// ================= weight prep: swizzled wfmt + mw2 + zerobuf =================
__global__ void weight_prep_kernel(const float* __restrict__ weight,
                                   __hip_bfloat16* __restrict__ wfmt,
                                   float* __restrict__ mw2sum,
                                   float* __restrict__ zerobuf) {
    __shared__ float red[256];
    int o = blockIdx.x, t = threadIdx.x;
    if (o == 0 && t < 64) zerobuf[t] = 0.f;
    const float* wrow = weight + ((size_t)o * FINN + t) * 9;
    float wv[9];
    float mx = 0.f;
    #pragma unroll
    for (int k = 0; k < 9; ++k) { wv[k] = wrow[k]; mx = fmaxf(mx, fabsf(wv[k])); }
    red[t] = mx;
    __syncthreads();
    for (int k = 128; k > 0; k >>= 1) {
        if (t < k) red[t] = fmaxf(red[t], red[t + k]);
        __syncthreads();
    }
    float scale = (1.0f / 48.0f) / red[0];
    int obi = o >> 6, ol = o & 63, ch = t >> 5, il = t & 31;
    int slot = (il >> 3) ^ ((ol >> 1) & 3);
    char* basep = (char*)wfmt + (size_t)obi * 294912 + (size_t)ch * 36864
                + (size_t)ol * 64 + slot * 16 + (il & 7) * 2;
    float s2 = 0.f;
    #pragma unroll
    for (int tap = 0; tap < 9; ++tap) {
        float m = wv[tap] * scale;
        s2 += m * m;
        *(__hip_bfloat16*)(basep + tap * 4096) = __float2bfloat16(m);
    }
    mw2sum[(size_t)o * FINN + t] = s2;
}

// ================= style MLP layer (parallel over j across blocks) =================
__global__ __launch_bounds__(256) void style_layer_kernel(
    const float* __restrict__ in, const float* __restrict__ w,
    const float* __restrict__ bias, float* __restrict__ out,
    int in_dim_v4, int out_dim, float scale, int do_lrelu) {
    int t = threadIdx.x;
    int jl = t >> 4, kl = t & 15;
    int j = blockIdx.x * 16 + jl;
    int b = blockIdx.y;
    const float4* inr = (const float4*)(in + (size_t)b * (in_dim_v4 * 4));
    const float4* wr  = (const float4*)(w + (size_t)j * (in_dim_v4 * 4));
    float sum = 0.f;
    #pragma unroll 4
    for (int kb = kl; kb < in_dim_v4; kb += 16) {
        float4 wv = wr[kb], iv = inr[kb];
        sum += wv.x * iv.x + wv.y * iv.y + wv.z * iv.z + wv.w * iv.w;
    }
    #pragma unroll
    for (int off = 8; off >= 1; off >>= 1)
        sum += __shfl_xor(sum, off, 16);
    if (kl == 0) {
        float v = sum * scale + bias[j];
        if (do_lrelu && v < 0.f) v *= 0.2f;
        out[(size_t)b * out_dim + j] = v;
    }
}

// ================= fused inf-norm + dcoef =================
__global__ __launch_bounds__(256) void norm_dcoef_kernel(
    const float* __restrict__ sty, const float* __restrict__ mw2,
    float* __restrict__ snorm, float* __restrict__ dco) {
    __shared__ float red[256];
    __shared__ float s2[256];
    int b = blockIdx.x, t = threadIdx.x;
    float v = sty[(size_t)b * FINN + t];
    red[t] = fabsf(v);
    __syncthreads();
    for (int k = 128; k > 0; k >>= 1) {
        if (t < k) red[t] = fmaxf(red[t], red[t + k]);
        __syncthreads();
    }
    float sv = v / red[0];
    snorm[(size_t)b * FINN + t] = sv;
    s2[t] = sv * sv;
    __syncthreads();
    const float4* m2 = (const float4*)(mw2 + (size_t)t * FINN);
    const float4* sq = (const float4*)s2;
    float sum = 0.f;
    #pragma unroll 8
    for (int kb = 0; kb < 64; ++kb) {
        float4 a = m2[kb], xq = sq[kb];
        sum += a.x * xq.x + a.y * xq.y + a.z * xq.z + a.w * xq.w;
    }
    dco[(size_t)b * FOUTN + t] = rsqrtf(sum + 1e-8f);
}

// ================= x NCHW fp32 -> swizzled chunk-major bf16 xm =================
__global__ __launch_bounds__(256) void xcvt_kernel(const float* __restrict__ x,
                                                   const float* __restrict__ sn,
                                                   char* __restrict__ xm) {
    __shared__ float tile[64][65];
    int h = blockIdx.x, b = blockIdx.y;
    int t = threadIdx.x;
    int wl_ = t & 63, ig = t >> 6;
    char* xmb = xm + (size_t)b * 2097152;
    for (int icb = 0; icb < 4; ++icb) {
        if (icb) __syncthreads();
        #pragma unroll
        for (int p = 0; p < 16; ++p) {
            int i_l = p * 4 + ig;
            int i = icb * 64 + i_l;
            tile[i_l][wl_] = x[((size_t)(b * FINN + i)) * 4096 + h * 64 + wl_]
                             * sn[(size_t)b * FINN + i];
        }
        __syncthreads();
        #pragma unroll
        for (int rep = 0; rep < 2; ++rep) {
            int g = rep * 256 + t;     // 0..511
            int w = g >> 3, q8 = g & 7;
            int chunk = icb * 2 + (q8 >> 2), iq = q8 & 3;
            int slot = iq ^ (((h + 1) + ((w + 1) >> 1)) & 3);
            short tmp[8];
            #pragma unroll
            for (int j = 0; j < 8; ++j) {
                __hip_bfloat16 hb = __float2bfloat16(tile[q8 * 8 + j][w]);
                tmp[j] = *(short*)&hb;
            }
            char* dst = xmb + (size_t)chunk * 262144 + (size_t)(h * 64 + w) * 64 + slot * 16;
            *(bf16x8*)dst = *(bf16x8*)tmp;
        }
    }
}

// ================= global_load_lds helper =================
__device__ __forceinline__ void gl_lds16(const void* g, void* l) {
    __builtin_amdgcn_global_load_lds(
        (const __attribute__((address_space(1))) unsigned int*)g,
        (__attribute__((address_space(3))) unsigned int*)l, 16, 0, 0);
}

// ---- fragment helpers: 2-row (N=128) register tile ----
__device__ __forceinline__ void rd_tap2(bf16x8* xf, bf16x8* wf,
                                        const char* xsb, const char* wlb,
                                        int wid, int l15, int lg, int wfrag,
                                        int kh, int kw) {
    int tap = kh * 3 + kw;
    int pa = (wid * 2 + kh) * 66 + kw + l15;
    int pb = pa + 66;
    int xa = pa * 64 + ((lg ^ ((pa >> 1) & 3)) << 4);
    int xb = pb * 64 + ((lg ^ ((pb >> 1) & 3)) << 4);
    #pragma unroll
    for (int nt = 0; nt < 4; ++nt)
        xf[nt] = *(const bf16x8*)(xsb + xa + nt * 1024);
    #pragma unroll
    for (int nt = 0; nt < 4; ++nt)
        xf[4 + nt] = *(const bf16x8*)(xsb + xb + nt * 1024);
    #pragma unroll
    for (int mt = 0; mt < 4; ++mt)
        wf[mt] = *(const bf16x8*)(wlb + tap * 4096 + mt * 1024 + wfrag);
}

__device__ __forceinline__ void mm_tap2(f32x4 acc[4][8], const bf16x8* xf, const bf16x8* wf) {
    #pragma unroll
    for (int mt = 0; mt < 4; ++mt)
        #pragma unroll
        for (int nt = 0; nt < 8; ++nt)
            acc[mt][nt] = __builtin_amdgcn_mfma_f32_16x16x32_bf16(
                wf[mt], xf[nt], acc[mt][nt], 0, 0, 0);
}

// pipelined step: read next tap's 12 frags, wait for current tap's, MFMA current
#define STEP2(XFN, WFN, KH, KW, XFC, WFC)                               \
    rd_tap2(XFN, WFN, xs, wlb, wid, l15, lg, wfrag, KH, KW);            \
    __builtin_amdgcn_sched_barrier(0);                                  \
    asm volatile("s_waitcnt lgkmcnt(12)" ::: "memory");                 \
    __builtin_amdgcn_sched_barrier(0);                                  \
    __builtin_amdgcn_s_setprio(1);                                      \
    mm_tap2(acc, XFC, WFC);                                             \
    __builtin_amdgcn_s_setprio(0);

// ================= MFMA conv: 16-row block, 2 rows/wave, w-dbuf =================
// grid (4 htile, 4 obi, 16 b) = 256 blocks (1/CU), 512 threads (8 waves).
// __launch_bounds__(512,1): 1 block/CU -> 256-VGPR budget (512,2 capped at 128 and spilled).
__global__ __launch_bounds__(512, 1) void mconv_kernel(
    const char* __restrict__ xm, const char* __restrict__ wfmt,
    const float* __restrict__ dco, float* __restrict__ y) {
    __shared__ char xs[76032];      // 18 rows x 66 cols x 64B, swizzled slots
    __shared__ char wl[2][36864];   // dbuf [tap 9][o 64][slot 4] granules

    int t = threadIdx.x;
    int lane = t & 63;
    int wid = t >> 6;
    int h0 = blockIdx.x * 16;
    int obi = blockIdx.y;
    int b = blockIdx.z;

    // zero halo columns (c=0,65) for all rows; never staged
    if (t < 144) {
        int r = t >> 3, sub = t & 7;
        int col = (sub >> 2) * 65, slot = sub & 3;
        *(i32x4*)(xs + ((r * 66 + col) * 4 + slot) * 16) = (i32x4){0, 0, 0, 0};
    }
    // zero out-of-range full rows (r=0 at htile 0; r=17 at htile 3); staging skips them
    if (h0 == 0) {
        for (int e = t; e < 256; e += 512)
            *(i32x4*)(xs + ((0 * 66 + 1 + (e >> 2)) * 4 + (e & 3)) * 16) = (i32x4){0, 0, 0, 0};
    }
    if (h0 == 48) {
        for (int e = t; e < 256; e += 512)
            *(i32x4*)(xs + ((17 * 66 + 1 + (e >> 2)) * 4 + (e & 3)) * 16) = (i32x4){0, 0, 0, 0};
    }

    // x staging: 72 issues/chunk (18 rows x 4 quarters), 9 per wave.
    // Offsets are wave-uniform -> force into SGPRs via readfirstlane (saves ~18 VGPRs).
    const char* xmb = xm + (size_t)b * 2097152 + lane * 16;
    unsigned xoff[9], xdst[9];
    #pragma unroll
    for (int q = 0; q < 9; ++q) {
        int idx = wid * 9 + q;
        int r = idx >> 2, quarter = idx & 3;
        int gh = h0 - 1 + r;
        bool v = (gh >= 0) && (gh < HH);
        xoff[q] = (unsigned)__builtin_amdgcn_readfirstlane(
            v ? (int)((gh * 64 + quarter * 16) * 64) : (int)0xFFFFFFFF);
        xdst[q] = (unsigned)__builtin_amdgcn_readfirstlane(
            (int)((r * 66 + 1) * 64 + quarter * 1024));
    }
    // w staging: 36 issues/chunk; waves 0..3 take 5, waves 4..7 take 4
    const char* wlane = wfmt + (size_t)obi * 294912 + lane * 16;

    f32x4 acc[4][8] = {};
    int l15 = lane & 15, lg = lane >> 4;
    int wfrag = l15 * 64 + ((lg ^ ((l15 >> 1) & 3)) << 4);

    // ---- prologue: stage w chunk 0 into wl[0] ----
    #pragma unroll
    for (int q = 0; q < 5; ++q) {
        int idx = wid + q * 8;
        if (idx < 36) gl_lds16(wlane + idx * 1024, wl[0] + idx * 1024);
    }
    wlane += 36864;

    for (int ch = 0; ch < 8; ++ch) {
        int cur = ch & 1;
        // x for this chunk (oldest in queue after prev-w)
        const char* xch = xmb + (size_t)ch * 262144;
        #pragma unroll
        for (int q = 0; q < 9; ++q)
            if (xoff[q] != 0xFFFFFFFFu) gl_lds16(xch + xoff[q], xs + xdst[q]);
        // w for next chunk (newest; stays in flight across barrier+compute)
        if (ch < 7) {
            #pragma unroll
            for (int q = 0; q < 5; ++q) {
                int idx = wid + q * 8;
                if (idx < 36) gl_lds16(wlane + idx * 1024, wl[cur ^ 1] + idx * 1024);
            }
            wlane += 36864;
            if (wid < 4) asm volatile("s_waitcnt vmcnt(5)" ::: "memory");
            else         asm volatile("s_waitcnt vmcnt(4)" ::: "memory");
        } else {
            asm volatile("s_waitcnt vmcnt(0)" ::: "memory");
        }
        asm volatile("s_waitcnt lgkmcnt(0)" ::: "memory");  // halo ds_writes (ch 0)
        __builtin_amdgcn_s_barrier();
        __builtin_amdgcn_sched_barrier(0);

        const char* wlb = wl[cur];
        // ---- tap pipeline: 2 frag banks, counted lgkm waits ----
        bf16x8 xf0[8], wf0[4], xf1[8], wf1[4];
        rd_tap2(xf0, wf0, xs, wlb, wid, l15, lg, wfrag, 0, 0);
        STEP2(xf1, wf1, 0, 1, xf0, wf0)
        STEP2(xf0, wf0, 0, 2, xf1, wf1)
        STEP2(xf1, wf1, 1, 0, xf0, wf0)
        STEP2(xf0, wf0, 1, 1, xf1, wf1)
        STEP2(xf1, wf1, 1, 2, xf0, wf0)
        STEP2(xf0, wf0, 2, 0, xf1, wf1)
        STEP2(xf1, wf1, 2, 1, xf0, wf0)
        STEP2(xf0, wf0, 2, 2, xf1, wf1)
        __builtin_amdgcn_sched_barrier(0);
        asm volatile("s_waitcnt lgkmcnt(0)" ::: "memory");
        __builtin_amdgcn_sched_barrier(0);
        __builtin_amdgcn_s_setprio(1);
        mm_tap2(acc, xf0, wf0);
        __builtin_amdgcn_s_setprio(0);

        __builtin_amdgcn_s_barrier();   // release xs and wl[cur] for overwrite
        __builtin_amdgcn_sched_barrier(0);
    }

    // epilogue: demod + store (2 rows per wave)
    const float* dcb = dco + (size_t)b * FOUTN + obi * 64;
    #pragma unroll
    for (int rr = 0; rr < 2; ++rr) {
        float* yb = y + (((size_t)b * FOUTN + obi * 64) * HH + (h0 + wid * 2 + rr)) * WW;
        #pragma unroll
        for (int mt = 0; mt < 4; ++mt) {
            #pragma unroll
            for (int j = 0; j < 4; ++j) {
                int o_l = mt * 16 + lg * 4 + j;
                float d = dcb[o_l];
                #pragma unroll
                for (int n4 = 0; n4 < 4; ++n4)
                    yb[(size_t)o_l * 4096 + n4 * 16 + l15] = acc[mt][rr * 4 + n4][j] * d;
            }
        }
    }
}

extern "C" void kernel_launch(void* const* d_in, const int* in_sizes, int n_in,
                              void* d_out, int out_size, void* d_ws, size_t ws_size,
                              hipStream_t stream) {
    const float* x      = (const float*)d_in[0];
    const float* lat    = (const float*)d_in[1];
    const float* weight = (const float*)d_in[2];
    const float* wsm    = (const float*)d_in[3];
    const float* bsm    = (const float*)d_in[4];
    const float* wff    = (const float*)d_in[5];
    const float* bff    = (const float*)d_in[6];
    float* y = (float*)d_out;

    char* base = (char*)d_ws;
    float* zerobuf = (float*)(base + WS_ZERO);
    float* mw2     = (float*)(base + WS_MW2);
    float* dco     = (float*)(base + WS_DCO);
    float* snorm   = (float*)(base + WS_SNORM);
    __hip_bfloat16* wfmt = (__hip_bfloat16*)(base + WS_WFMT);
    char* xm       = base + WS_XM;
    float* hA      = (float*)(base + WS_HA);
    float* hB      = (float*)(base + WS_HB);
    float* sty     = (float*)(base + WS_STY);

    const float eq = 0.044194173824159216f;  // 1/sqrt(512)

    weight_prep_kernel<<<FOUTN, 256, 0, stream>>>(weight, wfmt, mw2, zerobuf);
    style_layer_kernel<<<dim3(LATN / 16, NB), 256, 0, stream>>>(
        lat, wsm + 0 * (size_t)LATN * LATN, bsm + 0 * LATN, hA, LATN / 4, LATN, eq, 1);
    style_layer_kernel<<<dim3(LATN / 16, NB), 256, 0, stream>>>(
        hA, wsm + 1 * (size_t)LATN * LATN, bsm + 1 * LATN, hB, LATN / 4, LATN, eq, 1);
    style_layer_kernel<<<dim3(LATN / 16, NB), 256, 0, stream>>>(
        hB, wsm + 2 * (size_t)LATN * LATN, bsm + 2 * LATN, hA, LATN / 4, LATN, eq, 1);
    style_layer_kernel<<<dim3(LATN / 16, NB), 256, 0, stream>>>(
        hA, wsm + 3 * (size_t)LATN * LATN, bsm + 3 * LATN, hB, LATN / 4, LATN, eq, 1);
    style_layer_kernel<<<dim3(FINN / 16, NB), 256, 0, stream>>>(
        hB, wff, bff, sty, LATN / 4, FINN, 1.0f, 0);
    norm_dcoef_kernel<<<NB, 256, 0, stream>>>(sty, mw2, snorm, dco);
    xcvt_kernel<<<dim3(HH, NB), 256, 0, stream>>>(x, snorm, xm);
    mconv_kernel<<<dim3(4, 4, NB), 512, 0, stream>>>(xm, (const char*)wfmt, dco, y);
}

// Round 10
// 114.998 us; speedup vs baseline: 1.2908x; 1.0962x over previous
//
#include <hip/hip_runtime.h>
#include <hip/hip_bf16.h>

#define LATN 512
#define FINN 256
#define FOUTN 256
#define NB 16
#define HH 64
#define WW 64

typedef __attribute__((ext_vector_type(8))) short bf16x8;
typedef __attribute__((ext_vector_type(4))) float f32x4;
typedef __attribute__((ext_vector_type(4))) int i32x4;

// ------- workspace byte offsets -------
#define WS_ZERO   0           // 256 B
#define WS_MW2    4096        // 256*256*4 = 262144
#define WS_DCO    266240      // 16*256*4  = 16384
#define WS_SNORM  282624      // 16*256*4  = 16384
#define WS_WFMT   299008      // 4*294912  = 1179648
#define WS_XM     1478656     // 16*2097152 = 33554432
// style ping-pong buffers ALIAS the xm region (dead until xcvt runs):
#define WS_HA     (WS_XM)            // 16*512*4
#define WS_HB     (WS_XM + 32768)    // 16*512*4
#define WS_STY    (WS_XM + 65536)    // 16*256*4
// xm layout  : [b][chunk(8)][pos(4096)][slot(4)] granules of 16B (8 bf16 ch), slot = iq ^ sigma(h,w)
// wfmt layout: [obi(4)][chunk(8)][tap(9)][ol(64)][slot(4)] granules, slot = iq ^ ((ol>>1)&3)

// ================= weight prep: swizzled wfmt + mw2 + zerobuf =================
__global__ void weight_prep_kernel(const float* __restrict__ weight,
                                   __hip_bfloat16* __restrict__ wfmt,
                                   float* __restrict__ mw2sum,
                                   float* __restrict__ zerobuf) {
    __shared__ float red[256];
    int o = blockIdx.x, t = threadIdx.x;
    if (o == 0 && t < 64) zerobuf[t] = 0.f;
    const float* wrow = weight + ((size_t)o * FINN + t) * 9;
    float wv[9];
    float mx = 0.f;
    #pragma unroll
    for (int k = 0; k < 9; ++k) { wv[k] = wrow[k]; mx = fmaxf(mx, fabsf(wv[k])); }
    red[t] = mx;
    __syncthreads();
    for (int k = 128; k > 0; k >>= 1) {
        if (t < k) red[t] = fmaxf(red[t], red[t + k]);
        __syncthreads();
    }
    float scale = (1.0f / 48.0f) / red[0];
    int obi = o >> 6, ol = o & 63, ch = t >> 5, il = t & 31;
    int slot = (il >> 3) ^ ((ol >> 1) & 3);
    char* basep = (char*)wfmt + (size_t)obi * 294912 + (size_t)ch * 36864
                + (size_t)ol * 64 + slot * 16 + (il & 7) * 2;
    float s2 = 0.f;
    #pragma unroll
    for (int tap = 0; tap < 9; ++tap) {
        float m = wv[tap] * scale;
        s2 += m * m;
        *(__hip_bfloat16*)(basep + tap * 4096) = __float2bfloat16(m);
    }
    mw2sum[(size_t)o * FINN + t] = s2;
}

// ================= style MLP layer (parallel over j across blocks) =================
__global__ __launch_bounds__(256) void style_layer_kernel(
    const float* __restrict__ in, const float* __restrict__ w,
    const float* __restrict__ bias, float* __restrict__ out,
    int in_dim_v4, int out_dim, float scale, int do_lrelu) {
    int t = threadIdx.x;
    int jl = t >> 4, kl = t & 15;
    int j = blockIdx.x * 16 + jl;
    int b = blockIdx.y;
    const float4* inr = (const float4*)(in + (size_t)b * (in_dim_v4 * 4));
    const float4* wr  = (const float4*)(w + (size_t)j * (in_dim_v4 * 4));
    float sum = 0.f;
    #pragma unroll 4
    for (int kb = kl; kb < in_dim_v4; kb += 16) {
        float4 wv = wr[kb], iv = inr[kb];
        sum += wv.x * iv.x + wv.y * iv.y + wv.z * iv.z + wv.w * iv.w;
    }
    #pragma unroll
    for (int off = 8; off >= 1; off >>= 1)
        sum += __shfl_xor(sum, off, 16);
    if (kl == 0) {
        float v = sum * scale + bias[j];
        if (do_lrelu && v < 0.f) v *= 0.2f;
        out[(size_t)b * out_dim + j] = v;
    }
}

// ================= fused inf-norm + dcoef =================
__global__ __launch_bounds__(256) void norm_dcoef_kernel(
    const float* __restrict__ sty, const float* __restrict__ mw2,
    float* __restrict__ snorm, float* __restrict__ dco) {
    __shared__ float red[256];
    __shared__ float s2[256];
    int b = blockIdx.x, t = threadIdx.x;
    float v = sty[(size_t)b * FINN + t];
    red[t] = fabsf(v);
    __syncthreads();
    for (int k = 128; k > 0; k >>= 1) {
        if (t < k) red[t] = fmaxf(red[t], red[t + k]);
        __syncthreads();
    }
    float sv = v / red[0];
    snorm[(size_t)b * FINN + t] = sv;
    s2[t] = sv * sv;
    __syncthreads();
    const float4* m2 = (const float4*)(mw2 + (size_t)t * FINN);
    const float4* sq = (const float4*)s2;
    float sum = 0.f;
    #pragma unroll 8
    for (int kb = 0; kb < 64; ++kb) {
        float4 a = m2[kb], xq = sq[kb];
        sum += a.x * xq.x + a.y * xq.y + a.z * xq.z + a.w * xq.w;
    }
    dco[(size_t)b * FOUTN + t] = rsqrtf(sum + 1e-8f);
}

// ================= x NCHW fp32 -> swizzled chunk-major bf16 xm =================
__global__ __launch_bounds__(256) void xcvt_kernel(const float* __restrict__ x,
                                                   const float* __restrict__ sn,
                                                   char* __restrict__ xm) {
    __shared__ float tile[64][65];
    int h = blockIdx.x, b = blockIdx.y;
    int t = threadIdx.x;
    int wl_ = t & 63, ig = t >> 6;
    char* xmb = xm + (size_t)b * 2097152;
    for (int icb = 0; icb < 4; ++icb) {
        if (icb) __syncthreads();
        #pragma unroll
        for (int p = 0; p < 16; ++p) {
            int i_l = p * 4 + ig;
            int i = icb * 64 + i_l;
            tile[i_l][wl_] = x[((size_t)(b * FINN + i)) * 4096 + h * 64 + wl_]
                             * sn[(size_t)b * FINN + i];
        }
        __syncthreads();
        #pragma unroll
        for (int rep = 0; rep < 2; ++rep) {
            int g = rep * 256 + t;     // 0..511
            int w = g >> 3, q8 = g & 7;
            int chunk = icb * 2 + (q8 >> 2), iq = q8 & 3;
            int slot = iq ^ (((h + 1) + ((w + 1) >> 1)) & 3);
            short tmp[8];
            #pragma unroll
            for (int j = 0; j < 8; ++j) {
                __hip_bfloat16 hb = __float2bfloat16(tile[q8 * 8 + j][w]);
                tmp[j] = *(short*)&hb;
            }
            char* dst = xmb + (size_t)chunk * 262144 + (size_t)(h * 64 + w) * 64 + slot * 16;
            *(bf16x8*)dst = *(bf16x8*)tmp;
        }
    }
}

// ================= global_load_lds helper =================
__device__ __forceinline__ void gl_lds16(const void* g, void* l) {
    __builtin_amdgcn_global_load_lds(
        (const __attribute__((address_space(1))) unsigned int*)g,
        (__attribute__((address_space(3))) unsigned int*)l, 16, 0, 0);
}

// ================= MFMA conv: 16-row block, 2 rows/wave, w-dbuf =================
// grid (4 htile, 4 obi, 16 b) = 256 blocks (1/CU), 512 threads (8 waves).
// Single fragment bank (48 VGPR) + staged lgkm waits: LDS-read-bound regime,
// so no tap-ahead pipeline — cross-wave (2/SIMD) overlap covers MFMA issue.
__global__ __launch_bounds__(512, 1) void mconv_kernel(
    const char* __restrict__ xm, const char* __restrict__ wfmt,
    const float* __restrict__ dco, float* __restrict__ y) {
    __shared__ char xs[76032];      // 18 rows x 66 cols x 64B, swizzled slots
    __shared__ char wl[2][36864];   // dbuf [tap 9][o 64][slot 4] granules

    int t = threadIdx.x;
    int lane = t & 63;
    int wid = t >> 6;
    int h0 = blockIdx.x * 16;
    int obi = blockIdx.y;
    int b = blockIdx.z;

    // zero halo columns (c=0,65) for all rows; never staged
    if (t < 144) {
        int r = t >> 3, sub = t & 7;
        int col = (sub >> 2) * 65, slot = sub & 3;
        *(i32x4*)(xs + ((r * 66 + col) * 4 + slot) * 16) = (i32x4){0, 0, 0, 0};
    }
    // zero out-of-range full rows (r=0 at htile 0; r=17 at htile 3); staging skips them
    if (h0 == 0) {
        for (int e = t; e < 256; e += 512)
            *(i32x4*)(xs + ((0 * 66 + 1 + (e >> 2)) * 4 + (e & 3)) * 16) = (i32x4){0, 0, 0, 0};
    }
    if (h0 == 48) {
        for (int e = t; e < 256; e += 512)
            *(i32x4*)(xs + ((17 * 66 + 1 + (e >> 2)) * 4 + (e & 3)) * 16) = (i32x4){0, 0, 0, 0};
    }

    // x staging: 72 issues/chunk (18 rows x 4 quarters), 9 per wave.
    // Offsets are wave-uniform -> force into SGPRs via readfirstlane.
    const char* xmb = xm + (size_t)b * 2097152 + lane * 16;
    unsigned xoff[9], xdst[9];
    #pragma unroll
    for (int q = 0; q < 9; ++q) {
        int idx = wid * 9 + q;
        int r = idx >> 2, quarter = idx & 3;
        int gh = h0 - 1 + r;
        bool v = (gh >= 0) && (gh < HH);
        xoff[q] = (unsigned)__builtin_amdgcn_readfirstlane(
            v ? (int)((gh * 64 + quarter * 16) * 64) : (int)0xFFFFFFFF);
        xdst[q] = (unsigned)__builtin_amdgcn_readfirstlane(
            (int)((r * 66 + 1) * 64 + quarter * 1024));
    }
    // w staging: 36 issues/chunk; waves 0..3 take 5, waves 4..7 take 4
    const char* wlane = wfmt + (size_t)obi * 294912 + lane * 16;

    f32x4 acc[4][8] = {};
    int l15 = lane & 15, lg = lane >> 4;
    int wfrag = l15 * 64 + ((lg ^ ((l15 >> 1) & 3)) << 4);

    // ---- prologue: stage w chunk 0 into wl[0] ----
    #pragma unroll
    for (int q = 0; q < 5; ++q) {
        int idx = wid + q * 8;
        if (idx < 36) gl_lds16(wlane + idx * 1024, wl[0] + idx * 1024);
    }
    wlane += 36864;

    for (int ch = 0; ch < 8; ++ch) {
        int cur = ch & 1;
        // x for this chunk (oldest in queue after prev-w)
        const char* xch = xmb + (size_t)ch * 262144;
        #pragma unroll
        for (int q = 0; q < 9; ++q)
            if (xoff[q] != 0xFFFFFFFFu) gl_lds16(xch + xoff[q], xs + xdst[q]);
        // w for next chunk (newest; stays in flight across barrier+compute)
        if (ch < 7) {
            #pragma unroll
            for (int q = 0; q < 5; ++q) {
                int idx = wid + q * 8;
                if (idx < 36) gl_lds16(wlane + idx * 1024, wl[cur ^ 1] + idx * 1024);
            }
            wlane += 36864;
            if (wid < 4) asm volatile("s_waitcnt vmcnt(5)" ::: "memory");
            else         asm volatile("s_waitcnt vmcnt(4)" ::: "memory");
        } else {
            asm volatile("s_waitcnt vmcnt(0)" ::: "memory");
        }
        asm volatile("s_waitcnt lgkmcnt(0)" ::: "memory");  // halo ds_writes (ch 0)
        __builtin_amdgcn_s_barrier();
        __builtin_amdgcn_sched_barrier(0);

        const char* wlb = wl[cur];
        // ---- per-tap: issue 12 reads [A, B-row0, B-row1], staged waits ----
        #pragma unroll
        for (int kh = 0; kh < 3; ++kh) {
            #pragma unroll
            for (int kw = 0; kw < 3; ++kw) {
                int tap = kh * 3 + kw;
                int pa = (wid * 2 + kh) * 66 + kw + l15;
                int pb = pa + 66;
                int xa = pa * 64 + ((lg ^ ((pa >> 1) & 3)) << 4);
                int xb = pb * 64 + ((lg ^ ((pb >> 1) & 3)) << 4);
                bf16x8 wf[4], x0[4], x1[4];
                #pragma unroll
                for (int mt = 0; mt < 4; ++mt)
                    wf[mt] = *(const bf16x8*)(wlb + tap * 4096 + mt * 1024 + wfrag);
                #pragma unroll
                for (int nt = 0; nt < 4; ++nt)
                    x0[nt] = *(const bf16x8*)(xs + xa + nt * 1024);
                #pragma unroll
                for (int nt = 0; nt < 4; ++nt)
                    x1[nt] = *(const bf16x8*)(xs + xb + nt * 1024);
                __builtin_amdgcn_sched_barrier(0);
                asm volatile("s_waitcnt lgkmcnt(4)" ::: "memory");  // A + B-row0 ready
                __builtin_amdgcn_sched_barrier(0);
                __builtin_amdgcn_s_setprio(1);
                #pragma unroll
                for (int mt = 0; mt < 4; ++mt)
                    #pragma unroll
                    for (int nt = 0; nt < 4; ++nt)
                        acc[mt][nt] = __builtin_amdgcn_mfma_f32_16x16x32_bf16(
                            wf[mt], x0[nt], acc[mt][nt], 0, 0, 0);
                __builtin_amdgcn_s_setprio(0);
                __builtin_amdgcn_sched_barrier(0);
                asm volatile("s_waitcnt lgkmcnt(0)" ::: "memory");  // B-row1 ready
                __builtin_amdgcn_sched_barrier(0);
                __builtin_amdgcn_s_setprio(1);
                #pragma unroll
                for (int mt = 0; mt < 4; ++mt)
                    #pragma unroll
                    for (int nt = 0; nt < 4; ++nt)
                        acc[mt][4 + nt] = __builtin_amdgcn_mfma_f32_16x16x32_bf16(
                            wf[mt], x1[nt], acc[mt][4 + nt], 0, 0, 0);
                __builtin_amdgcn_s_setprio(0);
            }
        }

        __builtin_amdgcn_s_barrier();   // release xs and wl[cur] for overwrite
        __builtin_amdgcn_sched_barrier(0);
    }

    // epilogue: demod + store (2 rows per wave)
    const float* dcb = dco + (size_t)b * FOUTN + obi * 64;
    #pragma unroll
    for (int rr = 0; rr < 2; ++rr) {
        float* yb = y + (((size_t)b * FOUTN + obi * 64) * HH + (h0 + wid * 2 + rr)) * WW;
        #pragma unroll
        for (int mt = 0; mt < 4; ++mt) {
            #pragma unroll
            for (int j = 0; j < 4; ++j) {
                int o_l = mt * 16 + lg * 4 + j;
                float d = dcb[o_l];
                #pragma unroll
                for (int n4 = 0; n4 < 4; ++n4)
                    yb[(size_t)o_l * 4096 + n4 * 16 + l15] = acc[mt][rr * 4 + n4][j] * d;
            }
        }
    }
}

extern "C" void kernel_launch(void* const* d_in, const int* in_sizes, int n_in,
                              void* d_out, int out_size, void* d_ws, size_t ws_size,
                              hipStream_t stream) {
    const float* x      = (const float*)d_in[0];
    const float* lat    = (const float*)d_in[1];
    const float* weight = (const float*)d_in[2];
    const float* wsm    = (const float*)d_in[3];
    const float* bsm    = (const float*)d_in[4];
    const float* wff    = (const float*)d_in[5];
    const float* bff    = (const float*)d_in[6];
    float* y = (float*)d_out;

    char* base = (char*)d_ws;
    float* zerobuf = (float*)(base + WS_ZERO);
    float* mw2     = (float*)(base + WS_MW2);
    float* dco     = (float*)(base + WS_DCO);
    float* snorm   = (float*)(base + WS_SNORM);
    __hip_bfloat16* wfmt = (__hip_bfloat16*)(base + WS_WFMT);
    char* xm       = base + WS_XM;
    float* hA      = (float*)(base + WS_HA);
    float* hB      = (float*)(base + WS_HB);
    float* sty     = (float*)(base + WS_STY);

    const float eq = 0.044194173824159216f;  // 1/sqrt(512)

    weight_prep_kernel<<<FOUTN, 256, 0, stream>>>(weight, wfmt, mw2, zerobuf);
    style_layer_kernel<<<dim3(LATN / 16, NB), 256, 0, stream>>>(
        lat, wsm + 0 * (size_t)LATN * LATN, bsm + 0 * LATN, hA, LATN / 4, LATN, eq, 1);
    style_layer_kernel<<<dim3(LATN / 16, NB), 256, 0, stream>>>(
        hA, wsm + 1 * (size_t)LATN * LATN, bsm + 1 * LATN, hB, LATN / 4, LATN, eq, 1);
    style_layer_kernel<<<dim3(LATN / 16, NB), 256, 0, stream>>>(
        hB, wsm + 2 * (size_t)LATN * LATN, bsm + 2 * LATN, hA, LATN / 4, LATN, eq, 1);
    style_layer_kernel<<<dim3(LATN / 16, NB), 256, 0, stream>>>(
        hA, wsm + 3 * (size_t)LATN * LATN, bsm + 3 * LATN, hB, LATN / 4, LATN, eq, 1);
    style_layer_kernel<<<dim3(FINN / 16, NB), 256, 0, stream>>>(
        hB, wff, bff, sty, LATN / 4, FINN, 1.0f, 0);
    norm_dcoef_kernel<<<NB, 256, 0, stream>>>(sty, mw2, snorm, dco);
    xcvt_kernel<<<dim3(HH, NB), 256, 0, stream>>>(x, snorm, xm);
    mconv_kernel<<<dim3(4, 4, NB), 512, 0, stream>>>(xm, (const char*)wfmt, dco, y);
}

// Round 11
// 112.381 us; speedup vs baseline: 1.3208x; 1.0233x over previous
//
#include <hip/hip_runtime.h>
#include <hip/hip_bf16.h>

#define LATN 512
#define FINN 256
#define FOUTN 256
#define NB 16
#define HH 64
#define WW 64

typedef __attribute__((ext_vector_type(8))) short bf16x8;
typedef __attribute__((ext_vector_type(4))) float f32x4;
typedef __attribute__((ext_vector_type(4))) int i32x4;

// ------- workspace byte offsets -------
#define WS_ZERO   0           // 256 B
#define WS_MW2    4096        // 256*256*4 = 262144
#define WS_DCO    266240      // 16*256*4  = 16384
#define WS_SNORM  282624      // 16*256*4  = 16384
#define WS_WFMT   299008      // 4*294912  = 1179648
#define WS_XM     1478656     // 16*2097152 = 33554432
// style ping-pong buffers ALIAS the xm region (dead until xcvt runs):
#define WS_HA     (WS_XM)            // 16*512*4
#define WS_HB     (WS_XM + 32768)    // 16*512*4
#define WS_STY    (WS_XM + 65536)    // 16*256*4
// xm layout  : [b][chunk(8)][pos(4096)][slot(4)] granules of 16B (8 bf16 ch), slot = iq ^ sigma(h,w)
// wfmt layout: [obi(4)][chunk(8)][tap(9)][ol(64)][slot(4)] granules, slot = iq ^ ((ol>>1)&3)

// ================= weight prep: swizzled wfmt + mw2 + zerobuf =================
__global__ void weight_prep_kernel(const float* __restrict__ weight,
                                   __hip_bfloat16* __restrict__ wfmt,
                                   float* __restrict__ mw2sum,
                                   float* __restrict__ zerobuf) {
    __shared__ float red[256];
    int o = blockIdx.x, t = threadIdx.x;
    if (o == 0 && t < 64) zerobuf[t] = 0.f;
    const float* wrow = weight + ((size_t)o * FINN + t) * 9;
    float wv[9];
    float mx = 0.f;
    #pragma unroll
    for (int k = 0; k < 9; ++k) { wv[k] = wrow[k]; mx = fmaxf(mx, fabsf(wv[k])); }
    red[t] = mx;
    __syncthreads();
    for (int k = 128; k > 0; k >>= 1) {
        if (t < k) red[t] = fmaxf(red[t], red[t + k]);
        __syncthreads();
    }
    float scale = (1.0f / 48.0f) / red[0];
    int obi = o >> 6, ol = o & 63, ch = t >> 5, il = t & 31;
    int slot = (il >> 3) ^ ((ol >> 1) & 3);
    char* basep = (char*)wfmt + (size_t)obi * 294912 + (size_t)ch * 36864
                + (size_t)ol * 64 + slot * 16 + (il & 7) * 2;
    float s2 = 0.f;
    #pragma unroll
    for (int tap = 0; tap < 9; ++tap) {
        float m = wv[tap] * scale;
        s2 += m * m;
        *(__hip_bfloat16*)(basep + tap * 4096) = __float2bfloat16(m);
    }
    mw2sum[(size_t)o * FINN + t] = s2;
}

// ================= style MLP layer (parallel over j across blocks) =================
__global__ __launch_bounds__(256) void style_layer_kernel(
    const float* __restrict__ in, const float* __restrict__ w,
    const float* __restrict__ bias, float* __restrict__ out,
    int in_dim_v4, int out_dim, float scale, int do_lrelu) {
    int t = threadIdx.x;
    int jl = t >> 4, kl = t & 15;
    int j = blockIdx.x * 16 + jl;
    int b = blockIdx.y;
    const float4* inr = (const float4*)(in + (size_t)b * (in_dim_v4 * 4));
    const float4* wr  = (const float4*)(w + (size_t)j * (in_dim_v4 * 4));
    float sum = 0.f;
    #pragma unroll 4
    for (int kb = kl; kb < in_dim_v4; kb += 16) {
        float4 wv = wr[kb], iv = inr[kb];
        sum += wv.x * iv.x + wv.y * iv.y + wv.z * iv.z + wv.w * iv.w;
    }
    #pragma unroll
    for (int off = 8; off >= 1; off >>= 1)
        sum += __shfl_xor(sum, off, 16);
    if (kl == 0) {
        float v = sum * scale + bias[j];
        if (do_lrelu && v < 0.f) v *= 0.2f;
        out[(size_t)b * out_dim + j] = v;
    }
}

// ================= fused inf-norm + dcoef =================
__global__ __launch_bounds__(256) void norm_dcoef_kernel(
    const float* __restrict__ sty, const float* __restrict__ mw2,
    float* __restrict__ snorm, float* __restrict__ dco) {
    __shared__ float red[256];
    __shared__ float s2[256];
    int b = blockIdx.x, t = threadIdx.x;
    float v = sty[(size_t)b * FINN + t];
    red[t] = fabsf(v);
    __syncthreads();
    for (int k = 128; k > 0; k >>= 1) {
        if (t < k) red[t] = fmaxf(red[t], red[t + k]);
        __syncthreads();
    }
    float sv = v / red[0];
    snorm[(size_t)b * FINN + t] = sv;
    s2[t] = sv * sv;
    __syncthreads();
    const float4* m2 = (const float4*)(mw2 + (size_t)t * FINN);
    const float4* sq = (const float4*)s2;
    float sum = 0.f;
    #pragma unroll 8
    for (int kb = 0; kb < 64; ++kb) {
        float4 a = m2[kb], xq = sq[kb];
        sum += a.x * xq.x + a.y * xq.y + a.z * xq.z + a.w * xq.w;
    }
    dco[(size_t)b * FOUTN + t] = rsqrtf(sum + 1e-8f);
}

// ================= x NCHW fp32 -> swizzled chunk-major bf16 xm =================
__global__ __launch_bounds__(256) void xcvt_kernel(const float* __restrict__ x,
                                                   const float* __restrict__ sn,
                                                   char* __restrict__ xm) {
    __shared__ float tile[64][65];
    int h = blockIdx.x, b = blockIdx.y;
    int t = threadIdx.x;
    int wl_ = t & 63, ig = t >> 6;
    char* xmb = xm + (size_t)b * 2097152;
    for (int icb = 0; icb < 4; ++icb) {
        if (icb) __syncthreads();
        #pragma unroll
        for (int p = 0; p < 16; ++p) {
            int i_l = p * 4 + ig;
            int i = icb * 64 + i_l;
            tile[i_l][wl_] = x[((size_t)(b * FINN + i)) * 4096 + h * 64 + wl_]
                             * sn[(size_t)b * FINN + i];
        }
        __syncthreads();
        #pragma unroll
        for (int rep = 0; rep < 2; ++rep) {
            int g = rep * 256 + t;     // 0..511
            int w = g >> 3, q8 = g & 7;
            int chunk = icb * 2 + (q8 >> 2), iq = q8 & 3;
            int slot = iq ^ (((h + 1) + ((w + 1) >> 1)) & 3);
            short tmp[8];
            #pragma unroll
            for (int j = 0; j < 8; ++j) {
                __hip_bfloat16 hb = __float2bfloat16(tile[q8 * 8 + j][w]);
                tmp[j] = *(short*)&hb;
            }
            char* dst = xmb + (size_t)chunk * 262144 + (size_t)(h * 64 + w) * 64 + slot * 16;
            *(bf16x8*)dst = *(bf16x8*)tmp;
        }
    }
}

// ================= global_load_lds helper =================
__device__ __forceinline__ void gl_lds16(const void* g, void* l) {
    __builtin_amdgcn_global_load_lds(
        (const __attribute__((address_space(1))) unsigned int*)g,
        (__attribute__((address_space(3))) unsigned int*)l, 16, 0, 0);
}

// ================= MFMA conv: 4-wave blocks, 2 blocks/CU for overlap =================
// grid (8 htile, 4 obi, 16 b) = 512 blocks, 256 threads (4 waves).
// Block: 8 output rows (2/wave) x 64 o x 64 w. LDS = 42.2K(xs) + 36.9K(wl) = 79.1KB
// -> 2 independent blocks/CU whose barriers interleave: one block's MFMA phase
// overlaps the other's stage/LDS-read phase (cross-block pipelining, m97-style).
__global__ __launch_bounds__(256, 2) void mconv_kernel(
    const char* __restrict__ xm, const char* __restrict__ wfmt,
    const float* __restrict__ dco, float* __restrict__ y) {
    __shared__ char xs[42240];   // 10 rows x 66 cols x 64B, swizzled slots
    __shared__ char wl[36864];   // [tap 9][o 64][slot 4] granules

    int t = threadIdx.x;
    int lane = t & 63;
    int wid = t >> 6;            // 0..3
    int h0 = blockIdx.x * 8;
    int obi = blockIdx.y;
    int b = blockIdx.z;

    // zero halo columns (c=0,65) for rows 0..9; never staged
    if (t < 80) {
        int r = t >> 3, sub = t & 7;
        int col = (sub >> 2) * 65, slot = sub & 3;
        *(i32x4*)(xs + ((r * 66 + col) * 4 + slot) * 16) = (i32x4){0, 0, 0, 0};
    }
    // zero out-of-range full rows (r=0 at htile 0; r=9 at htile 7); staging skips them
    if (h0 == 0) {
        int e = t;  // 256 threads, 256 granules
        *(i32x4*)(xs + ((0 * 66 + 1 + (e >> 2)) * 4 + (e & 3)) * 16) = (i32x4){0, 0, 0, 0};
    }
    if (h0 == 56) {
        int e = t;
        *(i32x4*)(xs + ((9 * 66 + 1 + (e >> 2)) * 4 + (e & 3)) * 16) = (i32x4){0, 0, 0, 0};
    }

    // x staging: 40 issues/chunk (10 rows x 4 quarters), 10 per wave.
    // Wave-uniform offsets -> SGPRs via readfirstlane; invalid rows = sentinel.
    const char* xmb = xm + (size_t)b * 2097152 + lane * 16;
    unsigned xoff[10], xdst[10];
    #pragma unroll
    for (int q = 0; q < 10; ++q) {
        int idx = wid * 10 + q;
        int r = idx >> 2, quarter = idx & 3;
        int gh = h0 - 1 + r;
        bool v = (gh >= 0) && (gh < HH);
        xoff[q] = (unsigned)__builtin_amdgcn_readfirstlane(
            v ? (int)((gh * 64 + quarter * 16) * 64) : (int)0xFFFFFFFF);
        xdst[q] = (unsigned)__builtin_amdgcn_readfirstlane(
            (int)((r * 66 + 1) * 64 + quarter * 1024));
    }
    // w staging: 36 issues/chunk, 9 per wave
    const char* wlane = wfmt + (size_t)obi * 294912 + lane * 16;

    f32x4 acc[4][8] = {};
    int l15 = lane & 15, lg = lane >> 4;
    int wfrag = l15 * 64 + ((lg ^ ((l15 >> 1) & 3)) << 4);

    for (int ch = 0; ch < 8; ++ch) {
        // ---- stage x + w for this chunk ----
        const char* xch = xmb + (size_t)ch * 262144;
        #pragma unroll
        for (int q = 0; q < 10; ++q)
            if (xoff[q] != 0xFFFFFFFFu) gl_lds16(xch + xoff[q], xs + xdst[q]);
        const char* wch = wlane + (size_t)ch * 36864;
        #pragma unroll
        for (int q = 0; q < 9; ++q)
            gl_lds16(wch + (wid + q * 4) * 1024, wl + (wid + q * 4) * 1024);
        asm volatile("s_waitcnt vmcnt(0) lgkmcnt(0)" ::: "memory");
        __builtin_amdgcn_s_barrier();
        __builtin_amdgcn_sched_barrier(0);

        // ---- compute: 9 taps, staged lgkm waits within tap ----
        #pragma unroll
        for (int kh = 0; kh < 3; ++kh) {
            #pragma unroll
            for (int kw = 0; kw < 3; ++kw) {
                int tap = kh * 3 + kw;
                int pa = (wid * 2 + kh) * 66 + kw + l15;
                int pb = pa + 66;
                int xa = pa * 64 + ((lg ^ ((pa >> 1) & 3)) << 4);
                int xb = pb * 64 + ((lg ^ ((pb >> 1) & 3)) << 4);
                bf16x8 wf[4], x0[4], x1[4];
                #pragma unroll
                for (int mt = 0; mt < 4; ++mt)
                    wf[mt] = *(const bf16x8*)(wl + tap * 4096 + mt * 1024 + wfrag);
                #pragma unroll
                for (int nt = 0; nt < 4; ++nt)
                    x0[nt] = *(const bf16x8*)(xs + xa + nt * 1024);
                #pragma unroll
                for (int nt = 0; nt < 4; ++nt)
                    x1[nt] = *(const bf16x8*)(xs + xb + nt * 1024);
                __builtin_amdgcn_sched_barrier(0);
                asm volatile("s_waitcnt lgkmcnt(4)" ::: "memory");  // wf + x0 ready
                __builtin_amdgcn_sched_barrier(0);
                __builtin_amdgcn_s_setprio(1);
                #pragma unroll
                for (int mt = 0; mt < 4; ++mt)
                    #pragma unroll
                    for (int nt = 0; nt < 4; ++nt)
                        acc[mt][nt] = __builtin_amdgcn_mfma_f32_16x16x32_bf16(
                            wf[mt], x0[nt], acc[mt][nt], 0, 0, 0);
                __builtin_amdgcn_s_setprio(0);
                __builtin_amdgcn_sched_barrier(0);
                asm volatile("s_waitcnt lgkmcnt(0)" ::: "memory");  // x1 ready
                __builtin_amdgcn_sched_barrier(0);
                __builtin_amdgcn_s_setprio(1);
                #pragma unroll
                for (int mt = 0; mt < 4; ++mt)
                    #pragma unroll
                    for (int nt = 0; nt < 4; ++nt)
                        acc[mt][4 + nt] = __builtin_amdgcn_mfma_f32_16x16x32_bf16(
                            wf[mt], x1[nt], acc[mt][4 + nt], 0, 0, 0);
                __builtin_amdgcn_s_setprio(0);
            }
        }

        __builtin_amdgcn_s_barrier();   // release xs/wl for next chunk's stage
        __builtin_amdgcn_sched_barrier(0);
    }

    // epilogue: demod + store (2 rows per wave)
    const float* dcb = dco + (size_t)b * FOUTN + obi * 64;
    #pragma unroll
    for (int rr = 0; rr < 2; ++rr) {
        float* yb = y + (((size_t)b * FOUTN + obi * 64) * HH + (h0 + wid * 2 + rr)) * WW;
        #pragma unroll
        for (int mt = 0; mt < 4; ++mt) {
            #pragma unroll
            for (int j = 0; j < 4; ++j) {
                int o_l = mt * 16 + lg * 4 + j;
                float d = dcb[o_l];
                #pragma unroll
                for (int n4 = 0; n4 < 4; ++n4)
                    yb[(size_t)o_l * 4096 + n4 * 16 + l15] = acc[mt][rr * 4 + n4][j] * d;
            }
        }
    }
}

extern "C" void kernel_launch(void* const* d_in, const int* in_sizes, int n_in,
                              void* d_out, int out_size, void* d_ws, size_t ws_size,
                              hipStream_t stream) {
    const float* x      = (const float*)d_in[0];
    const float* lat    = (const float*)d_in[1];
    const float* weight = (const float*)d_in[2];
    const float* wsm    = (const float*)d_in[3];
    const float* bsm    = (const float*)d_in[4];
    const float* wff    = (const float*)d_in[5];
    const float* bff    = (const float*)d_in[6];
    float* y = (float*)d_out;

    char* base = (char*)d_ws;
    float* zerobuf = (float*)(base + WS_ZERO);
    float* mw2     = (float*)(base + WS_MW2);
    float* dco     = (float*)(base + WS_DCO);
    float* snorm   = (float*)(base + WS_SNORM);
    __hip_bfloat16* wfmt = (__hip_bfloat16*)(base + WS_WFMT);
    char* xm       = base + WS_XM;
    float* hA      = (float*)(base + WS_HA);
    float* hB      = (float*)(base + WS_HB);
    float* sty     = (float*)(base + WS_STY);

    const float eq = 0.044194173824159216f;  // 1/sqrt(512)

    weight_prep_kernel<<<FOUTN, 256, 0, stream>>>(weight, wfmt, mw2, zerobuf);
    style_layer_kernel<<<dim3(LATN / 16, NB), 256, 0, stream>>>(
        lat, wsm + 0 * (size_t)LATN * LATN, bsm + 0 * LATN, hA, LATN / 4, LATN, eq, 1);
    style_layer_kernel<<<dim3(LATN / 16, NB), 256, 0, stream>>>(
        hA, wsm + 1 * (size_t)LATN * LATN, bsm + 1 * LATN, hB, LATN / 4, LATN, eq, 1);
    style_layer_kernel<<<dim3(LATN / 16, NB), 256, 0, stream>>>(
        hB, wsm + 2 * (size_t)LATN * LATN, bsm + 2 * LATN, hA, LATN / 4, LATN, eq, 1);
    style_layer_kernel<<<dim3(LATN / 16, NB), 256, 0, stream>>>(
        hA, wsm + 3 * (size_t)LATN * LATN, bsm + 3 * LATN, hB, LATN / 4, LATN, eq, 1);
    style_layer_kernel<<<dim3(FINN / 16, NB), 256, 0, stream>>>(
        hB, wff, bff, sty, LATN / 4, FINN, 1.0f, 0);
    norm_dcoef_kernel<<<NB, 256, 0, stream>>>(sty, mw2, snorm, dco);
    xcvt_kernel<<<dim3(HH, NB), 256, 0, stream>>>(x, snorm, xm);
    mconv_kernel<<<dim3(8, 4, NB), 256, 0, stream>>>(xm, (const char*)wfmt, dco, y);
}